// Round 4
// baseline (3548.026 us; speedup 1.0000x reference)
//
#include <hip/hip_runtime.h>
#include <math.h>

#define NN 100000
#define EE 1600000
#define F0 166
#define HID 76
#define H3 228
#define CHID 510
#define SLOPE 0.22916666666666666f
#define CAND_MAX 4096
#define NBIN 4096

__device__ __forceinline__ unsigned f2key(float f){
    unsigned u = __float_as_uint(f);
    return (u & 0x80000000u) ? ~u : (u | 0x80000000u);
}
__device__ __forceinline__ float key2f(unsigned k){
    unsigned u = (k & 0x80000000u) ? (k & 0x7fffffffu) : ~k;
    return __uint_as_float(u);
}

// ---- scorer norms: invn[i] = 1/||scorer_i|| ----
__global__ void scorer_norms_k(const float* __restrict__ s0, const float* __restrict__ s1,
                               float* __restrict__ outn){
    __shared__ float red[256];
    int tid = threadIdx.x;
    float a = 0.f;
    for (int k = tid; k < F0; k += 256) a += s0[k]*s0[k];
    red[tid] = a; __syncthreads();
    for (int s = 128; s > 0; s >>= 1){ if (tid < s) red[tid] += red[tid+s]; __syncthreads(); }
    if (tid == 0) outn[0] = 1.0f/sqrtf(red[0]);
    __syncthreads();
    float b = 0.f;
    for (int k = tid; k < HID; k += 256) b += s1[k]*s1[k];
    red[tid] = b; __syncthreads();
    for (int s = 128; s > 0; s >>= 1){ if (tid < s) red[tid] += red[tid+s]; __syncthreads(); }
    if (tid == 0) outn[1] = 1.0f/sqrtf(red[0]);
}

// ---- pad/transpose classifier weights: w1t[512][76] (j-major), b1p[512], w2p[1024] ----
__global__ void pad_k(const float* __restrict__ w1, const float* __restrict__ b1,
                      const float* __restrict__ w2, float* __restrict__ w1t,
                      float* __restrict__ b1p, float* __restrict__ w2p){
    int idx = blockIdx.x*256 + threadIdx.x;
    if (idx < 512*HID){
        int j = idx / HID, k = idx - j*HID;
        w1t[idx] = (j < CHID) ? w1[k*CHID + j] : 0.f;
    }
    if (idx < 512)  b1p[idx] = (idx < CHID)   ? b1[idx] : 0.f;
    if (idx < 1024) w2p[idx] = (idx < CHID*2) ? w2[idx] : 0.f;
}

// ---- transpose evolved W[F][76] -> Wt chunk layout: Wt4[c*F + k] = W[k][4c..4c+3] ----
template<int F>
__global__ void transW_k(const float* __restrict__ W, float* __restrict__ Wt){
    int idx = blockIdx.x*256 + threadIdx.x;
    if (idx < F*HID){
        int k = idx / HID, j = idx - k*HID;
        int c = j >> 2, i = j & 3;
        Wt[(c*F + k)*4 + i] = W[idx];
    }
}

// ---- degree count ----
__global__ void deg_k(const int* __restrict__ src, const int* __restrict__ dst,
                      int* degO, int* degI){
    int e = blockIdx.x*256 + threadIdx.x;
    if (e < EE){
        atomicAdd(&degO[src[e]], 1);
        atomicAdd(&degI[dst[e]], 1);
    }
}

__global__ void norm_k(const int* __restrict__ degO, const int* __restrict__ degI,
                       float* __restrict__ nO, float* __restrict__ nI){
    int n = blockIdx.x*256 + threadIdx.x;
    if (n < NN){
        int o = degO[n]; if (o < 1) o = 1;
        int i = degI[n]; if (i < 1) i = 1;
        nO[n] = 1.0f/sqrtf((float)o);
        nI[n] = 1.0f/sqrtf((float)i);
    }
}

// ---- hierarchical exclusive scan of deg_in -> row_start ----
__global__ __launch_bounds__(1024) void scan_block_k(const int* __restrict__ deg,
                                                     int* __restrict__ rs, int* __restrict__ sums){
    __shared__ int sd[1024];
    int tid = threadIdx.x;
    int gid = blockIdx.x*1024 + tid;
    int v = (gid < NN) ? deg[gid] : 0;
    sd[tid] = v; __syncthreads();
    for (int off = 1; off < 1024; off <<= 1){
        int t = (tid >= off) ? sd[tid - off] : 0;
        __syncthreads();
        sd[tid] += t;
        __syncthreads();
    }
    if (gid < NN) rs[gid] = sd[tid] - v;
    if (tid == 1023) sums[blockIdx.x] = sd[tid];
}

__global__ void scan_sums_k(int* sums){
    if (threadIdx.x == 0){
        int acc = 0;
        for (int b = 0; b < 98; b++){ int v = sums[b]; sums[b] = acc; acc += v; }
    }
}

__global__ __launch_bounds__(1024) void add_off_k(int* __restrict__ rs, const int* __restrict__ sums){
    int gid = blockIdx.x*1024 + threadIdx.x;
    if (gid < NN) rs[gid] += sums[blockIdx.x];
}

// ---- CSR fill (bucket by dst, col = src) ----
__global__ void fill_k(const int* __restrict__ src, const int* __restrict__ dst,
                       const int* __restrict__ rs, int* fc, int* __restrict__ col){
    int e = blockIdx.x*256 + threadIdx.x;
    if (e < EE){
        int d = dst[e];
        int p = rs[d] + atomicAdd(&fc[d], 1);
        col[p] = src[e];
    }
}

// ---- scores (LDS-staged coalesced) + 12-bit-prefix histogram ----
template<int F, int PAD>
__global__ __launch_bounds__(256) void score_k(const float* __restrict__ x,
                                               const float* __restrict__ scorer,
                                               const float* __restrict__ invn,
                                               float* __restrict__ scores,
                                               unsigned* hist){
    __shared__ float xs[64*PAD];
    __shared__ float part[256];
    int tid = threadIdx.x;
    int n0 = blockIdx.x*64;
    int nodes = NN - n0; if (nodes > 64) nodes = 64;
    for (int idx = tid; idx < nodes*F; idx += 256){
        int n = idx / F, k = idx - n*F;
        xs[n*PAD + k] = x[(size_t)(n0+n)*F + k];
    }
    __syncthreads();
    int w = __builtin_amdgcn_readfirstlane(tid >> 6);
    int lane = tid & 63;
    int k0 = (F*w) >> 2, k1 = (F*(w+1)) >> 2;
    const float* xrow = xs + lane*PAD;
    float s = 0.f;
    for (int k = k0; k < k1; k++) s += xrow[k]*scorer[k];
    part[w*64 + lane] = s;
    __syncthreads();
    if (tid < 64 && n0 + tid < NN){
        float tot = (part[tid] + part[64+tid] + part[128+tid] + part[192+tid]) * invn[0];
        scores[n0 + tid] = tot;
        atomicAdd(&hist[f2key(tot) >> 20], 1u);
    }
}

// ---- find threshold bin (4096 bins) ----
__global__ void select_bin_k(const unsigned* __restrict__ hist, int* thr){
    __shared__ unsigned cs[256];
    int tid = threadIdx.x;
    unsigned s = 0;
    int base = NBIN - 1 - tid*16;
    for (int j = 0; j < 16; j++) s += hist[base - j];
    cs[tid] = s; __syncthreads();
    if (tid == 0){
        unsigned acc = 0; int c = 0;
        for (; c < 256; c++){ if (acc + cs[c] >= 76u) break; acc += cs[c]; }
        int b = NBIN - 1 - c*16;
        int sel = 0;
        for (int j = 0; j < 16; j++){
            acc += hist[b - j];
            if (acc >= 76u){ sel = b - j; break; }
        }
        *thr = sel;
    }
}

__global__ void compact_k(const float* __restrict__ scores, const int* __restrict__ thr,
                          float* __restrict__ cv, int* __restrict__ ci, int* cnt){
    int n = blockIdx.x*256 + threadIdx.x;
    if (n >= NN) return;
    float s = scores[n];
    if ((int)(f2key(s) >> 20) >= *thr){
        int p = atomicAdd(cnt, 1);
        if (p < CAND_MAX){ cv[p] = s; ci[p] = n; }
    }
}

// ---- exact top-76 (value desc, index asc), single wave ----
__global__ void topk_k(const float* __restrict__ cv, const int* __restrict__ ci,
                       const int* __restrict__ cnt, int* __restrict__ topidx,
                       float* __restrict__ tanhv){
    __shared__ unsigned long long keys[CAND_MAX];
    int tid = threadIdx.x;
    int M = *cnt; if (M > CAND_MAX) M = CAND_MAX;
    for (int i = tid; i < M; i += 64)
        keys[i] = ((unsigned long long)f2key(cv[i]) << 32) | (unsigned)(~ci[i]);
    __syncthreads();
    for (int j = 0; j < 76; j++){
        unsigned long long b = 0;
        for (int i = tid; i < M; i += 64){
            unsigned long long k = keys[i];
            if (k > b) b = k;
        }
        #pragma unroll
        for (int off = 32; off > 0; off >>= 1){
            unsigned long long o = __shfl_down(b, off, 64);
            if (o > b) b = o;
        }
        b = __shfl(b, 0, 64);
        if (tid == 0){
            unsigned idx = ~(unsigned)(b & 0xffffffffu);
            float v = key2f((unsigned)(b >> 32));
            topidx[j] = (int)idx;
            tanhv[j]  = tanhf(v);
        }
        for (int i = tid; i < M; i += 64) if (keys[i] == b) keys[i] = 0ull;
        __syncthreads();
    }
}

// ---- GRU weight evolution, one block per matrix row, in-place ----
template<int F>
__global__ void gru_k(const float* __restrict__ cur, const int* __restrict__ topidx,
                      const float* __restrict__ tanhv, float* __restrict__ W,
                      const float* __restrict__ wih, const float* __restrict__ whh,
                      const float* __restrict__ bih, const float* __restrict__ bhh){
    __shared__ float xr[HID], hr[HID], gx[H3], gh[H3];
    int r = blockIdx.x, tid = threadIdx.x;
    if (tid < HID){
        xr[tid] = cur[(size_t)topidx[tid]*F + r] * tanhv[tid];
        hr[tid] = W[r*HID + tid];
    }
    __syncthreads();
    if (tid < H3){
        const float* wi = wih + tid*HID;
        const float* wh = whh + tid*HID;
        float sa = 0.f, sb = 0.f;
        for (int k = 0; k < HID; k++){ sa += xr[k]*wi[k]; sb += hr[k]*wh[k]; }
        gx[tid] = bih[tid] + sa;
        gh[tid] = bhh[tid] + sb;
    }
    __syncthreads();
    if (tid < HID){
        float rr = 1.f/(1.f + expf(-(gx[tid] + gh[tid])));
        float zz = 1.f/(1.f + expf(-(gx[HID+tid] + gh[HID+tid])));
        float nn = tanhf(gx[2*HID+tid] + rr*gh[2*HID+tid]);
        W[r*HID + tid] = (1.f - zz)*nn + zz*hr[tid];
    }
}

// ---- h = (x @ W) * norm_out ----
// block = 64 nodes x 4 waves; x tile in LDS; wave w owns float4-chunks [5w,5w+5).
// Wt chunk layout: Wt4[c*F + k] -> 5 CONTIGUOUS wave-uniform scalar streams.
template<int F, int PAD>
__global__ __launch_bounds__(256) void gemm_k(const float* __restrict__ x,
                                              const float* __restrict__ Wt,
                                              const float* __restrict__ nO,
                                              float* __restrict__ h){
    __shared__ float xs[64*PAD];
    int tid = threadIdx.x;
    int n0 = blockIdx.x*64;
    int nodes = NN - n0; if (nodes > 64) nodes = 64;
    for (int idx = tid; idx < nodes*F; idx += 256){
        int n = idx / F, k = idx - n*F;
        xs[n*PAD + k] = x[(size_t)(n0+n)*F + k];
    }
    __syncthreads();
    int w = __builtin_amdgcn_readfirstlane(tid >> 6);
    int lane = tid & 63;
    int c0 = w*5;
    const float4* Wt4 = (const float4*)Wt;
    float4 acc[5];
    #pragma unroll
    for (int c = 0; c < 5; c++) acc[c] = make_float4(0.f,0.f,0.f,0.f);
    const float* xrow = xs + lane*PAD;
    for (int k = 0; k < F; k++){
        float xk = xrow[k];
        #pragma unroll
        for (int c = 0; c < 5; c++){
            float4 wv = Wt4[(c0 + c)*F + k];
            acc[c].x += xk*wv.x; acc[c].y += xk*wv.y;
            acc[c].z += xk*wv.z; acc[c].w += xk*wv.w;
        }
    }
    int n = n0 + lane;
    if (n < NN){
        float nm = nO[n];
        int nc = (w == 3) ? 4 : 5;
        float4* h4 = (float4*)h + (size_t)n*19 + c0;
        for (int c = 0; c < nc; c++){
            float4 a = acc[c];
            h4[c] = make_float4(a.x*nm, a.y*nm, a.z*nm, a.w*nm);
        }
    }
}

// ---- CSR aggregation + dst-norm + leaky, thread per (node, float4 chunk) ----
__global__ void agg_k(const int* __restrict__ rs, const int* __restrict__ degI,
                      const int* __restrict__ col, const float* __restrict__ h,
                      const float* __restrict__ nI, float* __restrict__ ft){
    int idx = blockIdx.x*256 + threadIdx.x;
    if (idx >= NN*19) return;
    int n = idx/19, c = idx%19;
    int st = rs[n], cnt = degI[n];
    const float4* h4 = (const float4*)h;
    float ax=0.f, ay=0.f, az=0.f, aw=0.f;
    for (int e = 0; e < cnt; e++){
        int s = col[st + e];
        float4 v = h4[(size_t)s*19 + c];
        ax += v.x; ay += v.y; az += v.z; aw += v.w;
    }
    float nm = nI[n];
    ax*=nm; ay*=nm; az*=nm; aw*=nm;
    ax = ax >= 0.f ? ax : ax*SLOPE;
    ay = ay >= 0.f ? ay : ay*SLOPE;
    az = az >= 0.f ? az : az*SLOPE;
    aw = aw >= 0.f ? aw : aw*SLOPE;
    ((float4*)ft)[(size_t)n*19 + c] = make_float4(ax,ay,az,aw);
}

// ---- classifier MLP ----
// block = 64 nodes x 4 waves; h tile in LDS; wave w handles j-groups g=w,w+4,...
// w1t is j-major: each group reads 1216 CONTIGUOUS bytes via scalar streams.
__global__ __launch_bounds__(256) void mlp_k(const float* __restrict__ ft,
                                             const float* __restrict__ w1t,
                                             const float* __restrict__ b1p,
                                             const float* __restrict__ w2p,
                                             const float* __restrict__ b2,
                                             float* __restrict__ out){
    __shared__ float hs[64*77];
    __shared__ float ap0[256], ap1[256];
    int tid = threadIdx.x;
    int n0 = blockIdx.x*64;
    int nodes = NN - n0; if (nodes > 64) nodes = 64;
    for (int idx = tid; idx < nodes*HID; idx += 256){
        int n = idx / HID, k = idx - n*HID;
        hs[n*77 + k] = ft[(size_t)(n0+n)*HID + k];
    }
    __syncthreads();
    int w = __builtin_amdgcn_readfirstlane(tid >> 6);
    int lane = tid & 63;
    const float* hrow = hs + lane*77;
    float a0 = 0.f, a1 = 0.f;
    for (int g = w; g < 128; g += 4){
        int j0 = g << 2;
        const float* wr = w1t + j0*HID;   // 4 contiguous rows of 76
        float s0 = b1p[j0], s1 = b1p[j0+1], s2 = b1p[j0+2], s3 = b1p[j0+3];
        for (int k = 0; k < HID; k++){
            float hv = hrow[k];
            s0 += hv*wr[k];
            s1 += hv*wr[HID + k];
            s2 += hv*wr[2*HID + k];
            s3 += hv*wr[3*HID + k];
        }
        s0 = fmaxf(s0, 0.f); s1 = fmaxf(s1, 0.f);
        s2 = fmaxf(s2, 0.f); s3 = fmaxf(s3, 0.f);
        a0 += s0*w2p[j0*2]   + s1*w2p[j0*2+2] + s2*w2p[j0*2+4] + s3*w2p[j0*2+6];
        a1 += s0*w2p[j0*2+1] + s1*w2p[j0*2+3] + s2*w2p[j0*2+5] + s3*w2p[j0*2+7];
    }
    ap0[w*64 + lane] = a0;
    ap1[w*64 + lane] = a1;
    __syncthreads();
    if (tid < 64 && n0 + tid < NN){
        float r0 = ap0[tid] + ap0[64+tid] + ap0[128+tid] + ap0[192+tid] + b2[0];
        float r1 = ap1[tid] + ap1[64+tid] + ap1[128+tid] + ap1[192+tid] + b2[1];
        out[(size_t)(n0+tid)*2]   = r0;
        out[(size_t)(n0+tid)*2+1] = r1;
    }
}

extern "C" void kernel_launch(void* const* d_in, const int* in_sizes, int n_in,
                              void* d_out, int out_size, void* d_ws, size_t ws_size,
                              hipStream_t stream)
{
    (void)in_sizes; (void)n_in; (void)out_size; (void)ws_size;
    const float* feats   = (const float*)d_in[0];
    const int*   src     = (const int*)d_in[1];
    const int*   dst     = (const int*)d_in[2];
    const float* scorer0 = (const float*)d_in[3];
    const float* scorer1 = (const float*)d_in[4];
    const float* gcnw[2] = {(const float*)d_in[5],  (const float*)d_in[6]};
    const float* wih[2]  = {(const float*)d_in[7],  (const float*)d_in[11]};
    const float* whh[2]  = {(const float*)d_in[8],  (const float*)d_in[12]};
    const float* bih[2]  = {(const float*)d_in[9],  (const float*)d_in[13]};
    const float* bhh[2]  = {(const float*)d_in[10], (const float*)d_in[14]};
    const float* w1 = (const float*)d_in[15];
    const float* b1 = (const float*)d_in[16];
    const float* w2 = (const float*)d_in[17];
    const float* b2 = (const float*)d_in[18];
    float* out = (float*)d_out;

    char* p = (char*)d_ws;
    auto alloc = [&](size_t bytes) -> void* {
        void* r = (void*)p;
        p += (bytes + 255) & ~(size_t)255;
        return r;
    };
    float* ft[3];
    for (int t = 0; t < 3; t++) ft[t] = (float*)alloc((size_t)NN*HID*4);
    float* hbuf = (float*)alloc((size_t)NN*HID*4);
    int* col[3];
    for (int t = 0; t < 3; t++) col[t] = (int*)alloc((size_t)EE*4);
    float *nO[3], *nI[3]; int *rs[3], *dI[3];
    for (int t = 0; t < 3; t++){
        nO[t] = (float*)alloc((size_t)NN*4);
        nI[t] = (float*)alloc((size_t)NN*4);
        rs[t] = (int*)alloc((size_t)NN*4);
        dI[t] = (int*)alloc((size_t)NN*4);
    }
    int*      dO     = (int*)alloc((size_t)NN*4);
    int*      fc     = (int*)alloc((size_t)NN*4);
    float*    scores = (float*)alloc((size_t)NN*4);
    unsigned* hist   = (unsigned*)alloc(NBIN*4);
    float*    cv     = (float*)alloc(CAND_MAX*4);
    int*      ci     = (int*)alloc(CAND_MAX*4);
    int*      ccnt   = (int*)alloc(256);
    int*      thr    = (int*)alloc(256);
    int*      topidx = (int*)alloc(128*4);
    float*    tanhv  = (float*)alloc(128*4);
    float*    Wbuf   = (float*)alloc((size_t)F0*HID*4 + 256);
    float*    Wt     = (float*)alloc((size_t)19*F0*16 + 4096); // chunk-layout, +pad for wave3 over-read
    float*    invn   = (float*)alloc(256);
    int*      sums   = (int*)alloc(128*4);
    float*    w1t    = (float*)alloc((size_t)512*HID*4);
    float*    b1p    = (float*)alloc(512*4);
    float*    w2p    = (float*)alloc(1024*4);

    const int gN  = (NN + 255)/256;
    const int gE  = (EE + 255)/256;
    const int gS  = 98;
    const int gA  = (NN*19 + 255)/256;
    const int gB  = (NN + 63)/64;
    const int gP  = (512*HID + 255)/256;
    const int gW0 = (F0*HID + 255)/256;
    const int gW1 = (HID*HID + 255)/256;

    scorer_norms_k<<<1,256,0,stream>>>(scorer0, scorer1, invn);
    pad_k<<<gP,256,0,stream>>>(w1, b1, w2, w1t, b1p, w2p);

    for (int t = 0; t < 3; t++){
        hipMemsetAsync(dO, 0, (size_t)NN*4, stream);
        hipMemsetAsync(dI[t], 0, (size_t)NN*4, stream);
        deg_k<<<gE,256,0,stream>>>(src + (size_t)t*EE, dst + (size_t)t*EE, dO, dI[t]);
        norm_k<<<gN,256,0,stream>>>(dO, dI[t], nO[t], nI[t]);
        scan_block_k<<<gS,1024,0,stream>>>(dI[t], rs[t], sums);
        scan_sums_k<<<1,64,0,stream>>>(sums);
        add_off_k<<<gS,1024,0,stream>>>(rs[t], sums);
        hipMemsetAsync(fc, 0, (size_t)NN*4, stream);
        fill_k<<<gE,256,0,stream>>>(src + (size_t)t*EE, dst + (size_t)t*EE, rs[t], fc, col[t]);
    }

    for (int i = 0; i < 2; i++){
        int F = (i == 0) ? F0 : HID;
        hipMemcpyAsync(Wbuf, gcnw[i], (size_t)F*HID*4, hipMemcpyDeviceToDevice, stream);
        for (int t = 0; t < 3; t++){
            const float* cur = (i == 0) ? (feats + (size_t)t*NN*F0) : ft[t];
            hipMemsetAsync(hist, 0, NBIN*4, stream);
            hipMemsetAsync(ccnt, 0, 4, stream);
            if (i == 0) score_k<F0,167><<<gB,256,0,stream>>>(cur, scorer0, invn+0, scores, hist);
            else        score_k<HID,77><<<gB,256,0,stream>>>(cur, scorer1, invn+1, scores, hist);
            select_bin_k<<<1,256,0,stream>>>(hist, thr);
            compact_k<<<gN,256,0,stream>>>(scores, thr, cv, ci, ccnt);
            topk_k<<<1,64,0,stream>>>(cv, ci, ccnt, topidx, tanhv);
            if (i == 0){
                gru_k<F0><<<F0,256,0,stream>>>(cur, topidx, tanhv, Wbuf, wih[i], whh[i], bih[i], bhh[i]);
                transW_k<F0><<<gW0,256,0,stream>>>(Wbuf, Wt);
                gemm_k<F0,167><<<gB,256,0,stream>>>(cur, Wt, nO[t], hbuf);
            } else {
                gru_k<HID><<<HID,256,0,stream>>>(cur, topidx, tanhv, Wbuf, wih[i], whh[i], bih[i], bhh[i]);
                transW_k<HID><<<gW1,256,0,stream>>>(Wbuf, Wt);
                gemm_k<HID,77><<<gB,256,0,stream>>>(cur, Wt, nO[t], hbuf);
            }
            agg_k<<<gA,256,0,stream>>>(rs[t], dI[t], col[t], hbuf, nI[t], ft[t]);
        }
    }

    mlp_k<<<gB,256,0,stream>>>(ft[2], w1t, b1p, w2p, b2, out);
}

// Round 5
// 3142.114 us; speedup vs baseline: 1.1292x; 1.1292x over previous
//
#include <hip/hip_runtime.h>
#include <math.h>

#define NN 100000
#define EE 1600000
#define F0 166
#define HID 76
#define H3 228
#define CHID 510
#define SLOPE 0.22916666666666666f
#define CAND_MAX 4096
#define NBIN 4096

__device__ __forceinline__ unsigned f2key(float f){
    unsigned u = __float_as_uint(f);
    return (u & 0x80000000u) ? ~u : (u | 0x80000000u);
}
__device__ __forceinline__ float key2f(unsigned k){
    unsigned u = (k & 0x80000000u) ? (k & 0x7fffffffu) : ~k;
    return __uint_as_float(u);
}

// ---- scorer norms: invn[i] = 1/||scorer_i|| ----
__global__ void scorer_norms_k(const float* __restrict__ s0, const float* __restrict__ s1,
                               float* __restrict__ outn){
    __shared__ float red[256];
    int tid = threadIdx.x;
    float a = 0.f;
    for (int k = tid; k < F0; k += 256) a += s0[k]*s0[k];
    red[tid] = a; __syncthreads();
    for (int s = 128; s > 0; s >>= 1){ if (tid < s) red[tid] += red[tid+s]; __syncthreads(); }
    if (tid == 0) outn[0] = 1.0f/sqrtf(red[0]);
    __syncthreads();
    float b = 0.f;
    for (int k = tid; k < HID; k += 256) b += s1[k]*s1[k];
    red[tid] = b; __syncthreads();
    for (int s = 128; s > 0; s >>= 1){ if (tid < s) red[tid] += red[tid+s]; __syncthreads(); }
    if (tid == 0) outn[1] = 1.0f/sqrtf(red[0]);
}

// ---- pad/transpose classifier weights: w1t[512][76] (j-major), b1p[512], w2p[1024] ----
__global__ void pad_k(const float* __restrict__ w1, const float* __restrict__ b1,
                      const float* __restrict__ w2, float* __restrict__ w1t,
                      float* __restrict__ b1p, float* __restrict__ w2p){
    int idx = blockIdx.x*256 + threadIdx.x;
    if (idx < 512*HID){
        int j = idx / HID, k = idx - j*HID;
        w1t[idx] = (j < CHID) ? w1[k*CHID + j] : 0.f;
    }
    if (idx < 512)  b1p[idx] = (idx < CHID)   ? b1[idx] : 0.f;
    if (idx < 1024) w2p[idx] = (idx < CHID*2) ? w2[idx] : 0.f;
}

// ---- degree count ----
__global__ void deg_k(const int* __restrict__ src, const int* __restrict__ dst,
                      int* degO, int* degI){
    int e = blockIdx.x*256 + threadIdx.x;
    if (e < EE){
        atomicAdd(&degO[src[e]], 1);
        atomicAdd(&degI[dst[e]], 1);
    }
}

__global__ void norm_k(const int* __restrict__ degO, const int* __restrict__ degI,
                       float* __restrict__ nO, float* __restrict__ nI){
    int n = blockIdx.x*256 + threadIdx.x;
    if (n < NN){
        int o = degO[n]; if (o < 1) o = 1;
        int i = degI[n]; if (i < 1) i = 1;
        nO[n] = 1.0f/sqrtf((float)o);
        nI[n] = 1.0f/sqrtf((float)i);
    }
}

// ---- hierarchical exclusive scan of deg_in -> row_start ----
__global__ __launch_bounds__(1024) void scan_block_k(const int* __restrict__ deg,
                                                     int* __restrict__ rs, int* __restrict__ sums){
    __shared__ int sd[1024];
    int tid = threadIdx.x;
    int gid = blockIdx.x*1024 + tid;
    int v = (gid < NN) ? deg[gid] : 0;
    sd[tid] = v; __syncthreads();
    for (int off = 1; off < 1024; off <<= 1){
        int t = (tid >= off) ? sd[tid - off] : 0;
        __syncthreads();
        sd[tid] += t;
        __syncthreads();
    }
    if (gid < NN) rs[gid] = sd[tid] - v;
    if (tid == 1023) sums[blockIdx.x] = sd[tid];
}

__global__ void scan_sums_k(int* sums){
    if (threadIdx.x == 0){
        int acc = 0;
        for (int b = 0; b < 98; b++){ int v = sums[b]; sums[b] = acc; acc += v; }
    }
}

__global__ __launch_bounds__(1024) void add_off_k(int* __restrict__ rs, const int* __restrict__ sums){
    int gid = blockIdx.x*1024 + threadIdx.x;
    if (gid < NN) rs[gid] += sums[blockIdx.x];
}

// ---- CSR fill (bucket by dst, col = src) ----
__global__ void fill_k(const int* __restrict__ src, const int* __restrict__ dst,
                       const int* __restrict__ rs, int* fc, int* __restrict__ col){
    int e = blockIdx.x*256 + threadIdx.x;
    if (e < EE){
        int d = dst[e];
        int p = rs[d] + atomicAdd(&fc[d], 1);
        col[p] = src[e];
    }
}

// ---- scores (LDS-staged coalesced) + 12-bit-prefix histogram ----
template<int F, int PAD>
__global__ __launch_bounds__(256) void score_k(const float* __restrict__ x,
                                               const float* __restrict__ scorer,
                                               const float* __restrict__ invn,
                                               float* __restrict__ scores,
                                               unsigned* hist){
    __shared__ float xs[64*PAD];
    __shared__ float part[256];
    int tid = threadIdx.x;
    int n0 = blockIdx.x*64;
    int nodes = NN - n0; if (nodes > 64) nodes = 64;
    for (int idx = tid; idx < nodes*F; idx += 256){
        int n = idx / F, k = idx - n*F;
        xs[n*PAD + k] = x[(size_t)(n0+n)*F + k];
    }
    __syncthreads();
    int w = __builtin_amdgcn_readfirstlane(tid >> 6);
    int lane = tid & 63;
    int k0 = (F*w) >> 2, k1 = (F*(w+1)) >> 2;
    const float* xrow = xs + lane*PAD;
    float s = 0.f;
    for (int k = k0; k < k1; k++) s += xrow[k]*scorer[k];
    part[w*64 + lane] = s;
    __syncthreads();
    if (tid < 64 && n0 + tid < NN){
        float tot = (part[tid] + part[64+tid] + part[128+tid] + part[192+tid]) * invn[0];
        scores[n0 + tid] = tot;
        atomicAdd(&hist[f2key(tot) >> 20], 1u);
    }
}

// ---- find threshold bin (4096 bins) ----
__global__ void select_bin_k(const unsigned* __restrict__ hist, int* thr){
    __shared__ unsigned cs[256];
    int tid = threadIdx.x;
    unsigned s = 0;
    int base = NBIN - 1 - tid*16;
    for (int j = 0; j < 16; j++) s += hist[base - j];
    cs[tid] = s; __syncthreads();
    if (tid == 0){
        unsigned acc = 0; int c = 0;
        for (; c < 256; c++){ if (acc + cs[c] >= 76u) break; acc += cs[c]; }
        int b = NBIN - 1 - c*16;
        int sel = 0;
        for (int j = 0; j < 16; j++){
            acc += hist[b - j];
            if (acc >= 76u){ sel = b - j; break; }
        }
        *thr = sel;
    }
}

__global__ void compact_k(const float* __restrict__ scores, const int* __restrict__ thr,
                          float* __restrict__ cv, int* __restrict__ ci, int* cnt){
    int n = blockIdx.x*256 + threadIdx.x;
    if (n >= NN) return;
    float s = scores[n];
    if ((int)(f2key(s) >> 20) >= *thr){
        int p = atomicAdd(cnt, 1);
        if (p < CAND_MAX){ cv[p] = s; ci[p] = n; }
    }
}

// ---- exact top-76 via O(M^2) rank computation (value desc, index asc) ----
__global__ __launch_bounds__(256) void topk_k(const float* __restrict__ cv,
                                              const int* __restrict__ ci,
                                              const int* __restrict__ cnt,
                                              int* __restrict__ topidx,
                                              float* __restrict__ tanhv){
    __shared__ unsigned long long keys[CAND_MAX];
    int tid = threadIdx.x;
    int M = *cnt; if (M > CAND_MAX) M = CAND_MAX;
    for (int i = tid; i < M; i += 256)
        keys[i] = ((unsigned long long)f2key(cv[i]) << 32) | (unsigned)(~ci[i]);
    __syncthreads();
    for (int i = tid; i < M; i += 256){
        unsigned long long ki = keys[i];
        int r = 0;
        for (int j = 0; j < M; j++) r += (keys[j] > ki) ? 1 : 0;
        if (r < 76){
            topidx[r] = (int)(~(unsigned)(ki & 0xffffffffu));
            tanhv[r]  = tanhf(key2f((unsigned)(ki >> 32)));
        }
    }
}

// ---- GRU weight evolution, one block per matrix row, in-place; also emits Wt ----
template<int F>
__global__ void gru_k(const float* __restrict__ cur, const int* __restrict__ topidx,
                      const float* __restrict__ tanhv, float* __restrict__ W,
                      float* __restrict__ Wt,
                      const float* __restrict__ wih, const float* __restrict__ whh,
                      const float* __restrict__ bih, const float* __restrict__ bhh){
    __shared__ float xr[HID], hr[HID], gx[H3], gh[H3];
    int r = blockIdx.x, tid = threadIdx.x;
    if (tid < HID){
        xr[tid] = cur[(size_t)topidx[tid]*F + r] * tanhv[tid];
        hr[tid] = W[r*HID + tid];
    }
    __syncthreads();
    if (tid < H3){
        const float* wi = wih + tid*HID;
        const float* wh = whh + tid*HID;
        float sa = 0.f, sb = 0.f;
        for (int k = 0; k < HID; k++){ sa += xr[k]*wi[k]; sb += hr[k]*wh[k]; }
        gx[tid] = bih[tid] + sa;
        gh[tid] = bhh[tid] + sb;
    }
    __syncthreads();
    if (tid < HID){
        float rr = 1.f/(1.f + expf(-(gx[tid] + gh[tid])));
        float zz = 1.f/(1.f + expf(-(gx[HID+tid] + gh[HID+tid])));
        float nn = tanhf(gx[2*HID+tid] + rr*gh[2*HID+tid]);
        float nv = (1.f - zz)*nn + zz*hr[tid];
        W[r*HID + tid] = nv;
        int c = tid >> 2, i = tid & 3;
        Wt[(c*F + r)*4 + i] = nv;    // chunk layout for gemm_k
    }
}

// ---- h = (x @ W) * norm_out ----
// block = 64 nodes x 4 waves; x tile in LDS; wave w owns float4-chunks [5w,5w+5).
// Wt chunk layout: Wt4[c*F + k] -> 5 CONTIGUOUS wave-uniform scalar streams.
template<int F, int PAD>
__global__ __launch_bounds__(256) void gemm_k(const float* __restrict__ x,
                                              const float* __restrict__ Wt,
                                              const float* __restrict__ nO,
                                              float* __restrict__ h){
    __shared__ float xs[64*PAD];
    int tid = threadIdx.x;
    int n0 = blockIdx.x*64;
    int nodes = NN - n0; if (nodes > 64) nodes = 64;
    for (int idx = tid; idx < nodes*F; idx += 256){
        int n = idx / F, k = idx - n*F;
        xs[n*PAD + k] = x[(size_t)(n0+n)*F + k];
    }
    __syncthreads();
    int w = __builtin_amdgcn_readfirstlane(tid >> 6);
    int lane = tid & 63;
    int c0 = w*5;
    const float4* Wt4 = (const float4*)Wt;
    float4 acc[5];
    #pragma unroll
    for (int c = 0; c < 5; c++) acc[c] = make_float4(0.f,0.f,0.f,0.f);
    const float* xrow = xs + lane*PAD;
    for (int k = 0; k < F; k++){
        float xk = xrow[k];
        #pragma unroll
        for (int c = 0; c < 5; c++){
            float4 wv = Wt4[(c0 + c)*F + k];
            acc[c].x += xk*wv.x; acc[c].y += xk*wv.y;
            acc[c].z += xk*wv.z; acc[c].w += xk*wv.w;
        }
    }
    int n = n0 + lane;
    if (n < NN){
        float nm = nO[n];
        int nc = (w == 3) ? 4 : 5;
        float4* h4 = (float4*)h + (size_t)n*19 + c0;
        for (int c = 0; c < nc; c++){
            float4 a = acc[c];
            h4[c] = make_float4(a.x*nm, a.y*nm, a.z*nm, a.w*nm);
        }
    }
}

// ---- CSR aggregation + dst-norm + leaky, thread per (node, float4 chunk) ----
__global__ void agg_k(const int* __restrict__ rs, const int* __restrict__ degI,
                      const int* __restrict__ col, const float* __restrict__ h,
                      const float* __restrict__ nI, float* __restrict__ ft){
    int idx = blockIdx.x*256 + threadIdx.x;
    if (idx >= NN*19) return;
    int n = idx/19, c = idx%19;
    int st = rs[n], cnt = degI[n];
    const float4* h4 = (const float4*)h;
    float ax=0.f, ay=0.f, az=0.f, aw=0.f;
    for (int e = 0; e < cnt; e++){
        int s = col[st + e];
        float4 v = h4[(size_t)s*19 + c];
        ax += v.x; ay += v.y; az += v.z; aw += v.w;
    }
    float nm = nI[n];
    ax*=nm; ay*=nm; az*=nm; aw*=nm;
    ax = ax >= 0.f ? ax : ax*SLOPE;
    ay = ay >= 0.f ? ay : ay*SLOPE;
    az = az >= 0.f ? az : az*SLOPE;
    aw = aw >= 0.f ? aw : aw*SLOPE;
    ((float4*)ft)[(size_t)n*19 + c] = make_float4(ax,ay,az,aw);
}

// ---- classifier MLP ----
// block = 64 nodes x 4 waves; h tile in LDS (unpadded, 304B rows, 16B aligned ->
// ds_read_b128); wave w handles j-groups g=w,w+4,... of 4 contiguous w1t rows.
__global__ __launch_bounds__(256) void mlp_k(const float* __restrict__ ft,
                                             const float* __restrict__ w1t,
                                             const float* __restrict__ b1p,
                                             const float* __restrict__ w2p,
                                             const float* __restrict__ b2,
                                             float* __restrict__ out){
    __shared__ float hs[64*HID];
    __shared__ float ap0[256], ap1[256];
    int tid = threadIdx.x;
    int n0 = blockIdx.x*64;
    int nodes = NN - n0; if (nodes > 64) nodes = 64;
    // linear float4 copy (hs layout == global layout)
    const float4* g4 = (const float4*)(ft + (size_t)n0*HID);
    float4* s4 = (float4*)hs;
    for (int idx = tid; idx < nodes*19; idx += 256) s4[idx] = g4[idx];
    __syncthreads();
    int w = __builtin_amdgcn_readfirstlane(tid >> 6);
    int lane = tid & 63;
    const float4* h4 = (const float4*)(hs + lane*HID);
    float a0 = 0.f, a1 = 0.f;
    for (int g = w; g < 128; g += 4){
        int j0 = g << 2;
        const float* wr = w1t + j0*HID;   // 4 contiguous rows of 76
        float s0 = b1p[j0], s1 = b1p[j0+1], s2 = b1p[j0+2], s3 = b1p[j0+3];
        #pragma unroll
        for (int k4 = 0; k4 < 19; k4++){
            float4 hv = h4[k4];
            int k = k4 << 2;
            s0 += hv.x*wr[k]         + hv.y*wr[k+1]         + hv.z*wr[k+2]         + hv.w*wr[k+3];
            s1 += hv.x*wr[HID+k]     + hv.y*wr[HID+k+1]     + hv.z*wr[HID+k+2]     + hv.w*wr[HID+k+3];
            s2 += hv.x*wr[2*HID+k]   + hv.y*wr[2*HID+k+1]   + hv.z*wr[2*HID+k+2]   + hv.w*wr[2*HID+k+3];
            s3 += hv.x*wr[3*HID+k]   + hv.y*wr[3*HID+k+1]   + hv.z*wr[3*HID+k+2]   + hv.w*wr[3*HID+k+3];
        }
        s0 = fmaxf(s0, 0.f); s1 = fmaxf(s1, 0.f);
        s2 = fmaxf(s2, 0.f); s3 = fmaxf(s3, 0.f);
        a0 += s0*w2p[j0*2]   + s1*w2p[j0*2+2] + s2*w2p[j0*2+4] + s3*w2p[j0*2+6];
        a1 += s0*w2p[j0*2+1] + s1*w2p[j0*2+3] + s2*w2p[j0*2+5] + s3*w2p[j0*2+7];
    }
    ap0[w*64 + lane] = a0;
    ap1[w*64 + lane] = a1;
    __syncthreads();
    if (tid < 64 && n0 + tid < NN){
        float r0 = ap0[tid] + ap0[64+tid] + ap0[128+tid] + ap0[192+tid] + b2[0];
        float r1 = ap1[tid] + ap1[64+tid] + ap1[128+tid] + ap1[192+tid] + b2[1];
        out[(size_t)(n0+tid)*2]   = r0;
        out[(size_t)(n0+tid)*2+1] = r1;
    }
}

extern "C" void kernel_launch(void* const* d_in, const int* in_sizes, int n_in,
                              void* d_out, int out_size, void* d_ws, size_t ws_size,
                              hipStream_t stream)
{
    (void)in_sizes; (void)n_in; (void)out_size; (void)ws_size;
    const float* feats   = (const float*)d_in[0];
    const int*   src     = (const int*)d_in[1];
    const int*   dst     = (const int*)d_in[2];
    const float* scorer0 = (const float*)d_in[3];
    const float* scorer1 = (const float*)d_in[4];
    const float* gcnw[2] = {(const float*)d_in[5],  (const float*)d_in[6]};
    const float* wih[2]  = {(const float*)d_in[7],  (const float*)d_in[11]};
    const float* whh[2]  = {(const float*)d_in[8],  (const float*)d_in[12]};
    const float* bih[2]  = {(const float*)d_in[9],  (const float*)d_in[13]};
    const float* bhh[2]  = {(const float*)d_in[10], (const float*)d_in[14]};
    const float* w1 = (const float*)d_in[15];
    const float* b1 = (const float*)d_in[16];
    const float* w2 = (const float*)d_in[17];
    const float* b2 = (const float*)d_in[18];
    float* out = (float*)d_out;

    char* p = (char*)d_ws;
    auto alloc = [&](size_t bytes) -> void* {
        void* r = (void*)p;
        p += (bytes + 255) & ~(size_t)255;
        return r;
    };
    float* ft[3];
    for (int t = 0; t < 3; t++) ft[t] = (float*)alloc((size_t)NN*HID*4);
    float* hbuf = (float*)alloc((size_t)NN*HID*4);
    int* col[3];
    for (int t = 0; t < 3; t++) col[t] = (int*)alloc((size_t)EE*4);
    float *nO[3], *nI[3]; int *rs[3];
    for (int t = 0; t < 3; t++){
        nO[t] = (float*)alloc((size_t)NN*4);
        nI[t] = (float*)alloc((size_t)NN*4);
        rs[t] = (int*)alloc((size_t)NN*4);
    }
    float*    scores = (float*)alloc((size_t)NN*4);
    float*    cv     = (float*)alloc(CAND_MAX*4);
    int*      ci     = (int*)alloc(CAND_MAX*4);
    int*      thr    = (int*)alloc(256);
    int*      topidx = (int*)alloc(128*4);
    float*    tanhv  = (float*)alloc(128*4);
    float*    Wbuf   = (float*)alloc((size_t)F0*HID*4 + 256);
    float*    Wt     = (float*)alloc((size_t)19*F0*16 + 4096); // chunk layout + wave3 over-read pad
    float*    invn   = (float*)alloc(256);
    int*      sums   = (int*)alloc(128*4);
    float*    w1t    = (float*)alloc((size_t)512*HID*4);
    float*    b1p    = (float*)alloc(512*4);
    float*    w2p    = (float*)alloc(1024*4);

    // ---- contiguous zero arena (one memset) ----
    char* zbase = p;
    int *dO[3], *dI[3], *fc[3];
    for (int t = 0; t < 3; t++) dO[t] = (int*)alloc((size_t)NN*4);
    for (int t = 0; t < 3; t++) dI[t] = (int*)alloc((size_t)NN*4);
    for (int t = 0; t < 3; t++) fc[t] = (int*)alloc((size_t)NN*4);
    unsigned* hist6 = (unsigned*)alloc((size_t)6*NBIN*4);
    int*      ccnt6 = (int*)alloc(6*256);
    size_t zsize = (size_t)(p - zbase);

    const int gN  = (NN + 255)/256;
    const int gE  = (EE + 255)/256;
    const int gS  = 98;
    const int gA  = (NN*19 + 255)/256;
    const int gB  = (NN + 63)/64;
    const int gP  = (512*HID + 255)/256;

    hipMemsetAsync(zbase, 0, zsize, stream);
    scorer_norms_k<<<1,256,0,stream>>>(scorer0, scorer1, invn);
    pad_k<<<gP,256,0,stream>>>(w1, b1, w2, w1t, b1p, w2p);

    for (int t = 0; t < 3; t++){
        deg_k<<<gE,256,0,stream>>>(src + (size_t)t*EE, dst + (size_t)t*EE, dO[t], dI[t]);
        norm_k<<<gN,256,0,stream>>>(dO[t], dI[t], nO[t], nI[t]);
        scan_block_k<<<gS,1024,0,stream>>>(dI[t], rs[t], sums);
        scan_sums_k<<<1,64,0,stream>>>(sums);
        add_off_k<<<gS,1024,0,stream>>>(rs[t], sums);
        fill_k<<<gE,256,0,stream>>>(src + (size_t)t*EE, dst + (size_t)t*EE, rs[t], fc[t], col[t]);
    }

    for (int i = 0; i < 2; i++){
        hipMemcpyAsync(Wbuf, gcnw[i], (size_t)((i==0)?F0:HID)*HID*4, hipMemcpyDeviceToDevice, stream);
        for (int t = 0; t < 3; t++){
            int q = i*3 + t;
            unsigned* hist = hist6 + (size_t)q*NBIN;
            int* ccnt = ccnt6 + q*64;
            const float* cur = (i == 0) ? (feats + (size_t)t*NN*F0) : ft[t];
            if (i == 0) score_k<F0,167><<<gB,256,0,stream>>>(cur, scorer0, invn+0, scores, hist);
            else        score_k<HID,77><<<gB,256,0,stream>>>(cur, scorer1, invn+1, scores, hist);
            select_bin_k<<<1,256,0,stream>>>(hist, thr);
            compact_k<<<gN,256,0,stream>>>(scores, thr, cv, ci, ccnt);
            topk_k<<<1,256,0,stream>>>(cv, ci, ccnt, topidx, tanhv);
            if (i == 0){
                gru_k<F0><<<F0,256,0,stream>>>(cur, topidx, tanhv, Wbuf, Wt, wih[i], whh[i], bih[i], bhh[i]);
                gemm_k<F0,167><<<gB,256,0,stream>>>(cur, Wt, nO[t], hbuf);
            } else {
                gru_k<HID><<<HID,256,0,stream>>>(cur, topidx, tanhv, Wbuf, Wt, wih[i], whh[i], bih[i], bhh[i]);
                gemm_k<HID,77><<<gB,256,0,stream>>>(cur, Wt, nO[t], hbuf);
            }
            agg_k<<<gA,256,0,stream>>>(rs[t], dI[t], col[t], hbuf, nI[t], ft[t]);
        }
    }

    mlp_k<<<gB,256,0,stream>>>(ft[2], w1t, b1p, w2p, b2, out);
}